// Round 4
// baseline (368.088 us; speedup 1.0000x reference)
//
#include <hip/hip_runtime.h>
#include <hip/hip_bf16.h>
#include <cstddef>

// Problem dims
#define H   512
#define E   256
#define V   32000
#define L   1024
#define B   64
#define KX  768      // E + H
#define M_TOT 65536  // L*B

typedef __attribute__((ext_vector_type(8))) short short8v;
typedef __attribute__((ext_vector_type(4))) float f32x4;

union fu32 { float f; unsigned u; };

__device__ __forceinline__ unsigned short f2bf(float x) {
    fu32 v; v.f = x;
    unsigned r = v.u + 0x7FFFu + ((v.u >> 16) & 1u);   // RNE
    return (unsigned short)(r >> 16);
}
__device__ __forceinline__ float bf2f(unsigned short b) {
    fu32 v; v.u = ((unsigned)b) << 16; return v.f;
}

// ---------------------------------------------------------------------------
// K-1: split enc (and W_attn[:, H:]) into bf16 hi/lo once.
// blocks 0..16383: enc (33554432 elems, 8/thread); 16384..16511: W slice.
// ---------------------------------------------------------------------------
__global__ __launch_bounds__(256) void k_split(const float* __restrict__ enc,
                                               const float* __restrict__ W_attn,
                                               unsigned short* __restrict__ enc_hi,
                                               unsigned short* __restrict__ enc_lo,
                                               unsigned short* __restrict__ Wh,
                                               unsigned short* __restrict__ Wl) {
    int bid = blockIdx.x;
    if (bid < 16384) {
        size_t base = ((size_t)bid * 256 + threadIdx.x) * 8;
        float4 x0 = *reinterpret_cast<const float4*>(&enc[base]);
        float4 x1 = *reinterpret_cast<const float4*>(&enc[base + 4]);
        float xs[8] = {x0.x, x0.y, x0.z, x0.w, x1.x, x1.y, x1.z, x1.w};
        union { short8v v; unsigned short u[8]; } hi, lo;
        #pragma unroll
        for (int i = 0; i < 8; ++i) {
            unsigned short hb = f2bf(xs[i]);
            hi.u[i] = hb;
            lo.u[i] = f2bf(xs[i] - bf2f(hb));
        }
        *reinterpret_cast<short8v*>(&enc_hi[base]) = hi.v;
        *reinterpret_cast<short8v*>(&enc_lo[base]) = lo.v;
    } else {
        int e0 = (bid - 16384) * 2048 + threadIdx.x * 8;   // 0..262143
        int j = e0 >> 9, k = e0 & 511;
        const float* src = &W_attn[(size_t)j * (2 * H) + H + k];
        float4 x0 = *reinterpret_cast<const float4*>(src);
        float4 x1 = *reinterpret_cast<const float4*>(src + 4);
        float xs[8] = {x0.x, x0.y, x0.z, x0.w, x1.x, x1.y, x1.z, x1.w};
        union { short8v v; unsigned short u[8]; } hi, lo;
        #pragma unroll
        for (int i = 0; i < 8; ++i) {
            unsigned short hb = f2bf(xs[i]);
            hi.u[i] = hb;
            lo.u[i] = f2bf(xs[i] - bf2f(hb));
        }
        *reinterpret_cast<short8v*>(&Wh[e0]) = hi.v;
        *reinterpret_cast<short8v*>(&Wl[e0]) = lo.v;
    }
}

// ---------------------------------------------------------------------------
// K0: build xprevT[k][b]
// ---------------------------------------------------------------------------
__global__ __launch_bounds__(256) void k_build(const int* __restrict__ inp,
                                               const float* __restrict__ loc,
                                               const float* __restrict__ hprev,
                                               const float* __restrict__ emb,
                                               float* __restrict__ xprevT) {
    int gid = blockIdx.x * 256 + threadIdx.x;
    int k = gid >> 6, b = gid & 63;
    float v;
    if (k < 256)      v = emb[(size_t)inp[b] * E + k];
    else if (k < 768) v = loc[b * H + (k - 256)];
    else              v = hprev[b * H + (k - 768)];
    xprevT[gid] = v;
}

// ---------------------------------------------------------------------------
// K1: LSTM cell (fp32). 4 independent accumulators to break the FMA chain.
// ---------------------------------------------------------------------------
__global__ __launch_bounds__(256) void k_lstm(const float* __restrict__ W_ih,
                                              const float* __restrict__ W_hh,
                                              const float* __restrict__ b_ih,
                                              const float* __restrict__ b_hh,
                                              const float* __restrict__ xprevT,
                                              const float* __restrict__ cprev,
                                              float* __restrict__ h_out,
                                              float* __restrict__ c_out,
                                              float* __restrict__ hnewT) {
    int u = blockIdx.x;
    int w = threadIdx.x >> 6;
    int b = threadIdx.x & 63;
    int j = w * 512 + u;
    float a0 = 0.f, a1 = 0.f, a2 = 0.f, a3 = 0.f;
    const float* Wr = &W_ih[(size_t)j * KX];
    for (int k = 0; k < KX; k += 4) {
        float4 wv = *reinterpret_cast<const float4*>(&Wr[k]);
        a0 += wv.x * xprevT[(k + 0) * 64 + b];
        a1 += wv.y * xprevT[(k + 1) * 64 + b];
        a2 += wv.z * xprevT[(k + 2) * 64 + b];
        a3 += wv.w * xprevT[(k + 3) * 64 + b];
    }
    const float* Wr2 = &W_hh[(size_t)j * H];
    const float* hT = &xprevT[KX * 64];
    for (int k = 0; k < H; k += 4) {
        float4 wv = *reinterpret_cast<const float4*>(&Wr2[k]);
        a0 += wv.x * hT[(k + 0) * 64 + b];
        a1 += wv.y * hT[(k + 1) * 64 + b];
        a2 += wv.z * hT[(k + 2) * 64 + b];
        a3 += wv.w * hT[(k + 3) * 64 + b];
    }
    float acc = b_ih[j] + b_hh[j] + ((a0 + a1) + (a2 + a3));
    __shared__ float gs[4][64];
    gs[w][b] = acc;
    __syncthreads();
    if (threadIdx.x < 64) {
        float ig = 1.f / (1.f + __expf(-gs[0][b]));
        float fg = 1.f / (1.f + __expf(-gs[1][b]));
        float gg = tanhf(gs[2][b]);
        float og = 1.f / (1.f + __expf(-gs[3][b]));
        float c = fg * cprev[b * H + u] + ig * gg;
        float h = og * tanhf(c);
        c_out[b * H + u] = c;
        h_out[b * H + u] = h;
        hnewT[u * 64 + b] = h;
    }
}

// ---------------------------------------------------------------------------
// K2: hW_jb[j][b] = b_attn[j] + sum_k h[b][k] * W_attn[j][k]
// ---------------------------------------------------------------------------
__global__ __launch_bounds__(256) void k_hw(const float* __restrict__ W_attn,
                                            const float* __restrict__ b_attn,
                                            const float* __restrict__ hT,
                                            float* __restrict__ hW_jb) {
    int j = blockIdx.x * 4 + (threadIdx.x >> 6);
    int b = threadIdx.x & 63;
    float a0 = 0.f, a1 = 0.f, a2 = 0.f, a3 = 0.f;
    const float* Wr = &W_attn[(size_t)j * (2 * H)];
    for (int k = 0; k < H; k += 4) {
        float4 wv = *reinterpret_cast<const float4*>(&Wr[k]);
        a0 += wv.x * hT[(k + 0) * 64 + b];
        a1 += wv.y * hT[(k + 1) * 64 + b];
        a2 += wv.z * hT[(k + 2) * 64 + b];
        a3 += wv.w * hT[(k + 3) * 64 + b];
    }
    hW_jb[j * 64 + b] = b_attn[j] + ((a0 + a1) + (a2 + a3));
}

// ---------------------------------------------------------------------------
// K3a (fast path): energy GEMM from prestaged bf16 hi/lo.
// grid 2048 = (mt 0..511) x (jt 0..3).  Block: 128 m-rows x 128 j.
// Reg-prefetch next K-tile issued after the stage barrier (hides under MFMA).
// Output: partial_e[jt][m] = sum_{j in tile} tanh(C+hW)*beta.
// ---------------------------------------------------------------------------
#define BKE 32
#define PITCH 40

__global__ __launch_bounds__(256, 3) void k_energy_pre(
        const unsigned short* __restrict__ enc_hi,
        const unsigned short* __restrict__ enc_lo,
        const unsigned short* __restrict__ Wh,
        const unsigned short* __restrict__ Wl,
        const float* __restrict__ hW,
        const float* __restrict__ beta,
        float* __restrict__ partial_e) {
    __shared__ unsigned short Ah[128 * PITCH];
    __shared__ unsigned short Al[128 * PITCH];
    __shared__ unsigned short Bh[128 * PITCH];
    __shared__ unsigned short Bl[128 * PITCH];
    __shared__ float red[2][128];

    const int tid  = threadIdx.x;
    const int lane = tid & 63;
    const int wave = tid >> 6;
    const int wm = wave >> 1;
    const int wn = wave & 1;
    const int mt = blockIdx.x >> 2;
    const int jt = blockIdx.x & 3;
    const int m0 = mt * 128;
    const int j0 = jt * 128;

    const int srow = tid >> 2;          // 0..63
    const int skc  = tid & 3;           // 0..3 (8-short chunk)

    short8v ra_h[2], ra_l[2], rb_h[2], rb_l[2];
    // prologue: load k0 = 0
    #pragma unroll
    for (int p = 0; p < 2; ++p) {
        int row = p * 64 + srow;
        size_t ao = (size_t)(m0 + row) * H + skc * 8;
        size_t bo = (size_t)(j0 + row) * H + skc * 8;
        ra_h[p] = *reinterpret_cast<const short8v*>(&enc_hi[ao]);
        ra_l[p] = *reinterpret_cast<const short8v*>(&enc_lo[ao]);
        rb_h[p] = *reinterpret_cast<const short8v*>(&Wh[bo]);
        rb_l[p] = *reinterpret_cast<const short8v*>(&Wl[bo]);
    }

    f32x4 acc[4][4];
    #pragma unroll
    for (int i = 0; i < 4; ++i)
        #pragma unroll
        for (int j = 0; j < 4; ++j) acc[i][j] = (f32x4){0.f, 0.f, 0.f, 0.f};

    for (int k0 = 0; k0 < H; k0 += BKE) {
        __syncthreads();                 // prev reads done / prefetch arrived
        #pragma unroll
        for (int p = 0; p < 2; ++p) {
            int off = (p * 64 + srow) * PITCH + skc * 8;
            *reinterpret_cast<short8v*>(&Ah[off]) = ra_h[p];
            *reinterpret_cast<short8v*>(&Al[off]) = ra_l[p];
            *reinterpret_cast<short8v*>(&Bh[off]) = rb_h[p];
            *reinterpret_cast<short8v*>(&Bl[off]) = rb_l[p];
        }
        __syncthreads();                 // writes visible
        if (k0 + BKE < H) {              // prefetch next tile (flies under MFMA)
            int kn = k0 + BKE;
            #pragma unroll
            for (int p = 0; p < 2; ++p) {
                int row = p * 64 + srow;
                size_t ao = (size_t)(m0 + row) * H + kn + skc * 8;
                size_t bo = (size_t)(j0 + row) * H + kn + skc * 8;
                ra_h[p] = *reinterpret_cast<const short8v*>(&enc_hi[ao]);
                ra_l[p] = *reinterpret_cast<const short8v*>(&enc_lo[ao]);
                rb_h[p] = *reinterpret_cast<const short8v*>(&Wh[bo]);
                rb_l[p] = *reinterpret_cast<const short8v*>(&Wl[bo]);
            }
        }
        const int fr = lane & 15;
        const int kb = (lane >> 4) * 8;
        short8v a_h[4], a_l[4], b_h[4], b_l[4];
        #pragma unroll
        for (int mf = 0; mf < 4; ++mf) {
            int off = (wm * 64 + mf * 16 + fr) * PITCH + kb;
            a_h[mf] = *reinterpret_cast<const short8v*>(&Ah[off]);
            a_l[mf] = *reinterpret_cast<const short8v*>(&Al[off]);
        }
        #pragma unroll
        for (int nf = 0; nf < 4; ++nf) {
            int off = (wn * 64 + nf * 16 + fr) * PITCH + kb;
            b_h[nf] = *reinterpret_cast<const short8v*>(&Bh[off]);
            b_l[nf] = *reinterpret_cast<const short8v*>(&Bl[off]);
        }
        #pragma unroll
        for (int mf = 0; mf < 4; ++mf)
            #pragma unroll
            for (int nf = 0; nf < 4; ++nf) {
                acc[mf][nf] = __builtin_amdgcn_mfma_f32_16x16x32_bf16(
                    a_h[mf], b_h[nf], acc[mf][nf], 0, 0, 0);
                acc[mf][nf] = __builtin_amdgcn_mfma_f32_16x16x32_bf16(
                    a_h[mf], b_l[nf], acc[mf][nf], 0, 0, 0);
                acc[mf][nf] = __builtin_amdgcn_mfma_f32_16x16x32_bf16(
                    a_l[mf], b_h[nf], acc[mf][nf], 0, 0, 0);
            }
    }
    // epilogue: psum[mf][r] = sum_j tanh(C + hW)*beta
    float psum[4][4];
    #pragma unroll
    for (int i = 0; i < 4; ++i)
        #pragma unroll
        for (int r = 0; r < 4; ++r) psum[i][r] = 0.f;
    #pragma unroll
    for (int nf = 0; nf < 4; ++nf) {
        int jj = j0 + wn * 64 + nf * 16 + (lane & 15);
        float bet = beta[jj];
        #pragma unroll
        for (int mf = 0; mf < 4; ++mf) {
            int b_base = (wm * 64 + mf * 16 + (lane >> 4) * 4) & 63;
            float4 hw4 = *reinterpret_cast<const float4*>(&hW[jj * 64 + b_base]);
            float hwv[4] = {hw4.x, hw4.y, hw4.z, hw4.w};
            #pragma unroll
            for (int r = 0; r < 4; ++r) {
                float e = acc[mf][nf][r] + hwv[r];
                float ex = __expf(2.f * e);
                psum[mf][r] += bet * (1.f - 2.f / (ex + 1.f));
            }
        }
    }
    #pragma unroll
    for (int mf = 0; mf < 4; ++mf)
        #pragma unroll
        for (int r = 0; r < 4; ++r) {
            float v = psum[mf][r];
            v += __shfl_xor(v, 1);
            v += __shfl_xor(v, 2);
            v += __shfl_xor(v, 4);
            v += __shfl_xor(v, 8);
            psum[mf][r] = v;
        }
    __syncthreads();
    if ((lane & 15) == 0) {
        #pragma unroll
        for (int mf = 0; mf < 4; ++mf)
            #pragma unroll
            for (int r = 0; r < 4; ++r)
                red[wn][wm * 64 + mf * 16 + (lane >> 4) * 4 + r] = psum[mf][r];
    }
    __syncthreads();
    if (tid < 128)
        partial_e[(size_t)jt * M_TOT + m0 + tid] = red[0][tid] + red[1][tid];
}

// ---------------------------------------------------------------------------
// K3b (fallback if ws too small): R2's convert-in-kernel energy GEMM.
// ---------------------------------------------------------------------------
__global__ __launch_bounds__(256, 2) void k_energy_mfma(
        const float* __restrict__ enc,
        const float* __restrict__ W_attn,
        const float* __restrict__ hW,
        const float* __restrict__ beta,
        float* __restrict__ energy) {
    __shared__ unsigned short Ah[128 * PITCH];
    __shared__ unsigned short Al[128 * PITCH];
    __shared__ unsigned short Bh[128 * PITCH];
    __shared__ unsigned short Bl[128 * PITCH];
    __shared__ float red[2][128];

    const int tid  = threadIdx.x;
    const int lane = tid & 63;
    const int wave = tid >> 6;
    const int wm = wave >> 1;
    const int wn = wave & 1;
    const int m0 = blockIdx.x * 128;
    const int srow = tid >> 2;
    const int skc  = tid & 3;

    float psum[4][4];
    #pragma unroll
    for (int i = 0; i < 4; ++i)
        #pragma unroll
        for (int r = 0; r < 4; ++r) psum[i][r] = 0.f;

    for (int jt = 0; jt < 4; ++jt) {
        const int j0 = jt * 128;
        f32x4 acc[4][4];
        #pragma unroll
        for (int i = 0; i < 4; ++i)
            #pragma unroll
            for (int j = 0; j < 4; ++j) acc[i][j] = (f32x4){0.f, 0.f, 0.f, 0.f};

        for (int k0 = 0; k0 < H; k0 += BKE) {
            __syncthreads();
            #pragma unroll
            for (int p = 0; p < 2; ++p) {
                int row = p * 64 + srow;
                {
                    const float* src = &enc[(size_t)(m0 + row) * H + k0 + skc * 8];
                    float4 x0 = *reinterpret_cast<const float4*>(src);
                    float4 x1 = *reinterpret_cast<const float4*>(src + 4);
                    float xs[8] = {x0.x, x0.y, x0.z, x0.w, x1.x, x1.y, x1.z, x1.w};
                    union { short8v v; unsigned short u[8]; } hi, lo;
                    #pragma unroll
                    for (int i = 0; i < 8; ++i) {
                        unsigned short hb = f2bf(xs[i]);
                        hi.u[i] = hb;
                        lo.u[i] = f2bf(xs[i] - bf2f(hb));
                    }
                    int off = row * PITCH + skc * 8;
                    *reinterpret_cast<short8v*>(&Ah[off]) = hi.v;
                    *reinterpret_cast<short8v*>(&Al[off]) = lo.v;
                }
                {
                    const float* src = &W_attn[(size_t)(j0 + row) * (2 * H) + H + k0 + skc * 8];
                    float4 x0 = *reinterpret_cast<const float4*>(src);
                    float4 x1 = *reinterpret_cast<const float4*>(src + 4);
                    float xs[8] = {x0.x, x0.y, x0.z, x0.w, x1.x, x1.y, x1.z, x1.w};
                    union { short8v v; unsigned short u[8]; } hi, lo;
                    #pragma unroll
                    for (int i = 0; i < 8; ++i) {
                        unsigned short hb = f2bf(xs[i]);
                        hi.u[i] = hb;
                        lo.u[i] = f2bf(xs[i] - bf2f(hb));
                    }
                    int off = row * PITCH + skc * 8;
                    *reinterpret_cast<short8v*>(&Bh[off]) = hi.v;
                    *reinterpret_cast<short8v*>(&Bl[off]) = lo.v;
                }
            }
            __syncthreads();
            const int fr = lane & 15;
            const int kb = (lane >> 4) * 8;
            short8v a_h[4], a_l[4], b_h[4], b_l[4];
            #pragma unroll
            for (int mf = 0; mf < 4; ++mf) {
                int off = (wm * 64 + mf * 16 + fr) * PITCH + kb;
                a_h[mf] = *reinterpret_cast<const short8v*>(&Ah[off]);
                a_l[mf] = *reinterpret_cast<const short8v*>(&Al[off]);
            }
            #pragma unroll
            for (int nf = 0; nf < 4; ++nf) {
                int off = (wn * 64 + nf * 16 + fr) * PITCH + kb;
                b_h[nf] = *reinterpret_cast<const short8v*>(&Bh[off]);
                b_l[nf] = *reinterpret_cast<const short8v*>(&Bl[off]);
            }
            #pragma unroll
            for (int mf = 0; mf < 4; ++mf)
                #pragma unroll
                for (int nf = 0; nf < 4; ++nf) {
                    acc[mf][nf] = __builtin_amdgcn_mfma_f32_16x16x32_bf16(
                        a_h[mf], b_h[nf], acc[mf][nf], 0, 0, 0);
                    acc[mf][nf] = __builtin_amdgcn_mfma_f32_16x16x32_bf16(
                        a_h[mf], b_l[nf], acc[mf][nf], 0, 0, 0);
                    acc[mf][nf] = __builtin_amdgcn_mfma_f32_16x16x32_bf16(
                        a_l[mf], b_h[nf], acc[mf][nf], 0, 0, 0);
                }
        }
        #pragma unroll
        for (int nf = 0; nf < 4; ++nf) {
            int jj = j0 + wn * 64 + nf * 16 + (lane & 15);
            float bet = beta[jj];
            #pragma unroll
            for (int mf = 0; mf < 4; ++mf) {
                int b_base = (wm * 64 + mf * 16 + (lane >> 4) * 4) & 63;
                float4 hw4 = *reinterpret_cast<const float4*>(&hW[jj * 64 + b_base]);
                float hwv[4] = {hw4.x, hw4.y, hw4.z, hw4.w};
                #pragma unroll
                for (int r = 0; r < 4; ++r) {
                    float e = acc[mf][nf][r] + hwv[r];
                    float ex = __expf(2.f * e);
                    psum[mf][r] += bet * (1.f - 2.f / (ex + 1.f));
                }
            }
        }
    }
    #pragma unroll
    for (int mf = 0; mf < 4; ++mf)
        #pragma unroll
        for (int r = 0; r < 4; ++r) {
            float v = psum[mf][r];
            v += __shfl_xor(v, 1);
            v += __shfl_xor(v, 2);
            v += __shfl_xor(v, 4);
            v += __shfl_xor(v, 8);
            psum[mf][r] = v;
        }
    __syncthreads();
    if ((lane & 15) == 0) {
        #pragma unroll
        for (int mf = 0; mf < 4; ++mf)
            #pragma unroll
            for (int r = 0; r < 4; ++r)
                red[wn][wm * 64 + mf * 16 + (lane >> 4) * 4 + r] = psum[mf][r];
    }
    __syncthreads();
    if (tid < 128) energy[m0 + tid] = red[0][tid] + red[1][tid];
}

// ---------------------------------------------------------------------------
// K4: softmax over l per b.  e[l] = sum_{nb<np} partial_e[nb][l*64+b]
// ---------------------------------------------------------------------------
__global__ __launch_bounds__(256) void k_softmax_l(const float* __restrict__ partial_e,
                                                   float* __restrict__ attn_w,
                                                   int np) {
    int b = blockIdx.x;
    int tid = threadIdx.x;
    float el[4];
    float m = -1e30f;
    #pragma unroll
    for (int i = 0; i < 4; ++i) {
        int l = i * 256 + tid;
        float e = 0.f;
        for (int nb = 0; nb < np; ++nb)
            e += partial_e[(size_t)nb * M_TOT + l * 64 + b];
        el[i] = e;
        m = fmaxf(m, e);
    }
    #pragma unroll
    for (int s = 1; s < 64; s <<= 1) m = fmaxf(m, __shfl_xor(m, s));
    __shared__ float redm[4];
    if ((tid & 63) == 0) redm[tid >> 6] = m;
    __syncthreads();
    m = fmaxf(fmaxf(redm[0], redm[1]), fmaxf(redm[2], redm[3]));
    float s = 0.f;
    #pragma unroll
    for (int i = 0; i < 4; ++i) { el[i] = __expf(el[i] - m); s += el[i]; }
    #pragma unroll
    for (int sh = 1; sh < 64; sh <<= 1) s += __shfl_xor(s, sh);
    __shared__ float reds[4];
    if ((tid & 63) == 0) reds[tid >> 6] = s;
    __syncthreads();
    s = reds[0] + reds[1] + reds[2] + reds[3];
    float inv = 1.f / s;
    #pragma unroll
    for (int i = 0; i < 4; ++i)
        attn_w[(i * 256 + tid) * 64 + b] = el[i] * inv;
}

// ---------------------------------------------------------------------------
// K5: context partials over l chunks.
// ---------------------------------------------------------------------------
__global__ __launch_bounds__(256) void k_ctx_part(const float* __restrict__ attn_w,
                                                  const float* __restrict__ enc,
                                                  float* __restrict__ ctx_part) {
    int chunk = blockIdx.x, b = blockIdx.y;
    int h = threadIdx.x * 2;
    float2 acc = {0.f, 0.f};
    for (int i = 0; i < 32; ++i) {
        int l = chunk * 32 + i;
        float w = attn_w[l * 64 + b];
        float2 e2 = *reinterpret_cast<const float2*>(
            &enc[((size_t)l * 64 + b) * H + h]);
        acc.x += w * e2.x;
        acc.y += w * e2.y;
    }
    *reinterpret_cast<float2*>(&ctx_part[((size_t)(chunk * 64 + b)) * H + h]) = acc;
}

__global__ __launch_bounds__(256) void k_ctx_reduce(const float* __restrict__ ctx_part,
                                                    float* __restrict__ ctxT) {
    int gid = blockIdx.x * 256 + threadIdx.x;
    int b = gid >> 9, h = gid & 511;
    float s = 0.f;
    for (int c = 0; c < 32; ++c)
        s += ctx_part[((size_t)(c * 64 + b)) * H + h];
    ctxT[h * 64 + b] = s;
}

// ---------------------------------------------------------------------------
// K6: co[b][j] = tanh([h | ctx] . W_oc[j] + b_oc[j])
// ---------------------------------------------------------------------------
__global__ __launch_bounds__(256) void k_co(const float* __restrict__ W_oc,
                                            const float* __restrict__ b_oc,
                                            const float* __restrict__ hT,
                                            const float* __restrict__ ctxT,
                                            float* __restrict__ co_out) {
    int j = blockIdx.x * 4 + (threadIdx.x >> 6);
    int b = threadIdx.x & 63;
    float a0 = 0.f, a1 = 0.f, a2 = 0.f, a3 = 0.f;
    const float* Wr = &W_oc[(size_t)j * (2 * H)];
    for (int k = 0; k < H; k += 4) {
        float4 wv = *reinterpret_cast<const float4*>(&Wr[k]);
        a0 += wv.x * hT[(k + 0) * 64 + b];
        a1 += wv.y * hT[(k + 1) * 64 + b];
        a2 += wv.z * hT[(k + 2) * 64 + b];
        a3 += wv.w * hT[(k + 3) * 64 + b];
    }
    const float* Wr2 = Wr + H;
    for (int k = 0; k < H; k += 4) {
        float4 wv = *reinterpret_cast<const float4*>(&Wr2[k]);
        a0 += wv.x * ctxT[(k + 0) * 64 + b];
        a1 += wv.y * ctxT[(k + 1) * 64 + b];
        a2 += wv.z * ctxT[(k + 2) * 64 + b];
        a3 += wv.w * ctxT[(k + 3) * 64 + b];
    }
    co_out[b * H + j] = tanhf(b_oc[j] + ((a0 + a1) + (a2 + a3)));
}

// ---------------------------------------------------------------------------
// K7: logits GEMM (fp32)
// ---------------------------------------------------------------------------
#define KT 32
__global__ __launch_bounds__(256) void k_logits(const float* __restrict__ co,
                                                const float* __restrict__ W_out,
                                                const float* __restrict__ b_out,
                                                float* __restrict__ logits) {
    const int nb = blockIdx.x;
    const int tid = threadIdx.x;
    const int tx = tid & 15;
    const int ty = tid >> 4;
    __shared__ float As[KT][68];
    __shared__ float Bs[KT][68];
    float acc[4][4] = {};
    const int j0 = nb * 64;
    for (int k0 = 0; k0 < H; k0 += KT) {
        #pragma unroll
        for (int it = 0; it < 2; ++it) {
            int idx = tid + it * 256;
            int r  = idx >> 3;
            int c4 = idx & 7;
            float4 a = *reinterpret_cast<const float4*>(
                &co[(size_t)r * H + k0 + c4 * 4]);
            As[c4 * 4 + 0][r] = a.x; As[c4 * 4 + 1][r] = a.y;
            As[c4 * 4 + 2][r] = a.z; As[c4 * 4 + 3][r] = a.w;
            float4 w = *reinterpret_cast<const float4*>(
                &W_out[(size_t)(j0 + r) * H + k0 + c4 * 4]);
            Bs[c4 * 4 + 0][r] = w.x; Bs[c4 * 4 + 1][r] = w.y;
            Bs[c4 * 4 + 2][r] = w.z; Bs[c4 * 4 + 3][r] = w.w;
        }
        __syncthreads();
        #pragma unroll
        for (int k = 0; k < KT; ++k) {
            float4 a4 = *reinterpret_cast<const float4*>(&As[k][ty * 4]);
            float4 b4 = *reinterpret_cast<const float4*>(&Bs[k][tx * 4]);
            float a[4] = {a4.x, a4.y, a4.z, a4.w};
            float b[4] = {b4.x, b4.y, b4.z, b4.w};
            #pragma unroll
            for (int i = 0; i < 4; ++i)
                #pragma unroll
                for (int j = 0; j < 4; ++j)
                    acc[i][j] += a[i] * b[j];
        }
        __syncthreads();
    }
    #pragma unroll
    for (int i = 0; i < 4; ++i) {
        int b = ty * 4 + i;
        float4 v;
        v.x = acc[i][0] + b_out[j0 + tx * 4 + 0];
        v.y = acc[i][1] + b_out[j0 + tx * 4 + 1];
        v.z = acc[i][2] + b_out[j0 + tx * 4 + 2];
        v.w = acc[i][3] + b_out[j0 + tx * 4 + 3];
        *reinterpret_cast<float4*>(&logits[(size_t)b * V + j0 + tx * 4]) = v;
    }
}

// ---------------------------------------------------------------------------
// K8: log_softmax per b over V.
// ---------------------------------------------------------------------------
__global__ __launch_bounds__(1024) void k_logsm(const float* __restrict__ logits,
                                                float* __restrict__ out) {
    int b = blockIdx.x;
    int tid = threadIdx.x;
    const float* row = &logits[(size_t)b * V];
    float m = -1e30f;
    for (int i = tid; i < V; i += 1024) m = fmaxf(m, row[i]);
    #pragma unroll
    for (int s = 1; s < 64; s <<= 1) m = fmaxf(m, __shfl_xor(m, s));
    __shared__ float redm[16];
    if ((tid & 63) == 0) redm[tid >> 6] = m;
    __syncthreads();
    m = redm[0];
    #pragma unroll
    for (int i = 1; i < 16; ++i) m = fmaxf(m, redm[i]);
    float s = 0.f;
    for (int i = tid; i < V; i += 1024) s += __expf(row[i] - m);
    #pragma unroll
    for (int sh = 1; sh < 64; sh <<= 1) s += __shfl_xor(s, sh);
    __shared__ float reds[16];
    if ((tid & 63) == 0) reds[tid >> 6] = s;
    __syncthreads();
    s = reds[0];
    #pragma unroll
    for (int i = 1; i < 16; ++i) s += reds[i];
    float lse = m + __logf(s);
    for (int i = tid; i < V; i += 1024)
        out[(size_t)b * V + i] = row[i] - lse;
}

// ---------------------------------------------------------------------------
extern "C" void kernel_launch(void* const* d_in, const int* in_sizes, int n_in,
                              void* d_out, int out_size, void* d_ws, size_t ws_size,
                              hipStream_t stream) {
    const int*   inp    = (const int*)  d_in[0];
    const float* loc    = (const float*)d_in[1];
    const float* hprev  = (const float*)d_in[2];
    const float* cprev  = (const float*)d_in[3];
    const float* enc    = (const float*)d_in[4];
    const float* emb    = (const float*)d_in[5];
    const float* W_ih   = (const float*)d_in[6];
    const float* W_hh   = (const float*)d_in[7];
    const float* b_ih   = (const float*)d_in[8];
    const float* b_hh   = (const float*)d_in[9];
    const float* W_attn = (const float*)d_in[10];
    const float* b_attn = (const float*)d_in[11];
    const float* beta   = (const float*)d_in[12];
    const float* W_oc   = (const float*)d_in[13];
    const float* b_oc   = (const float*)d_in[14];
    const float* W_out  = (const float*)d_in[15];
    const float* b_out  = (const float*)d_in[16];

    float* out = (float*)d_out;
    float* out_co = out + (size_t)B * V;
    float* out_h  = out_co + B * H;
    float* out_c  = out_h  + B * H;

    float* ws = (float*)d_ws;
    float* xprevT = ws;                                  //    81920
    float* hnewT  = xprevT + 1280 * 64;                  //    32768
    float* hW     = hnewT  + H * 64;                     //    32768
    float* pe     = hW     + H * 64;                     //  4*65536
    float* attnw  = pe     + 4 * M_TOT;                  //    65536
    float* ctxp   = attnw  + M_TOT;                      //  1048576
    float* ctxT   = ctxp   + 32 * 64 * H;                //    32768
    float* logits = ctxT   + H * 64;                     //  2048000
    float* ws_end = logits + (size_t)B * V;              // = ws + 3604480
    unsigned short* enc_hi = (unsigned short*)ws_end;    // 33554432 u16
    unsigned short* enc_lo = enc_hi + (size_t)M_TOT * H;
    unsigned short* Wh     = enc_lo + (size_t)M_TOT * H; //   262144 u16
    unsigned short* Wl     = Wh + H * H;

    const size_t NEED = (size_t)3604480 * 4               // fp32 scratch
                      + (size_t)2 * M_TOT * H * 2         // enc hi/lo
                      + (size_t)2 * H * H * 2;            // W hi/lo
    const bool pre = ws_size >= NEED;

    if (pre)
        k_split<<<16512, 256, 0, stream>>>(enc, W_attn, enc_hi, enc_lo, Wh, Wl);
    k_build <<<320, 256, 0, stream>>>(inp, loc, hprev, emb, xprevT);
    k_lstm  <<<512, 256, 0, stream>>>(W_ih, W_hh, b_ih, b_hh, xprevT, cprev,
                                      out_h, out_c, hnewT);
    k_hw    <<<128, 256, 0, stream>>>(W_attn, b_attn, hnewT, hW);
    if (pre) {
        k_energy_pre<<<2048, 256, 0, stream>>>(enc_hi, enc_lo, Wh, Wl, hW, beta, pe);
        k_softmax_l<<<64, 256, 0, stream>>>(pe, attnw, 4);
    } else {
        k_energy_mfma<<<512, 256, 0, stream>>>(enc, W_attn, hW, beta, pe);
        k_softmax_l<<<64, 256, 0, stream>>>(pe, attnw, 1);
    }
    k_ctx_part <<<dim3(32, 64), 256, 0, stream>>>(attnw, enc, ctxp);
    k_ctx_reduce<<<128, 256, 0, stream>>>(ctxp, ctxT);
    k_co    <<<128, 256, 0, stream>>>(W_oc, b_oc, hnewT, ctxT, out_co);
    k_logits<<<500, 256, 0, stream>>>(out_co, W_out, b_out, logits);
    k_logsm <<<64, 1024, 0, stream>>>(logits, out);
}

// Round 5
// 288.701 us; speedup vs baseline: 1.2750x; 1.2750x over previous
//
#include <hip/hip_runtime.h>
#include <hip/hip_bf16.h>
#include <cstddef>

// Problem dims
#define H   512
#define E   256
#define V   32000
#define L   1024
#define B   64
#define KX  768      // E + H
#define M_TOT 65536  // L*B

typedef __attribute__((ext_vector_type(8))) short short8v;
typedef __attribute__((ext_vector_type(4))) float f32x4;

union fu32 { float f; unsigned u; };

// Truncation split: hi = top 16 bits of x; lo = top 16 bits of (x - hi).
// Dropped residual ~2^-16 |x|; dropped ll product ~2^-16 |ab| -> negligible.
__device__ __forceinline__ void split2(float x, unsigned short& h, unsigned short& l) {
    fu32 v; v.f = x;
    h = (unsigned short)(v.u >> 16);
    fu32 hf; hf.u = v.u & 0xFFFF0000u;
    fu32 rv; rv.f = x - hf.f;
    l = (unsigned short)(rv.u >> 16);
}

// ---------------------------------------------------------------------------
// K-1: split W_attn[:, H:] into bf16 hi/lo once (1 MB total, ~2 us).
// 128 blocks x 256 threads x 8 elems.
// ---------------------------------------------------------------------------
__global__ __launch_bounds__(256) void k_split_w(const float* __restrict__ W_attn,
                                                 unsigned short* __restrict__ Wh,
                                                 unsigned short* __restrict__ Wl) {
    int e0 = blockIdx.x * 2048 + threadIdx.x * 8;      // 0..262143
    int j = e0 >> 9, k = e0 & 511;
    const float* src = &W_attn[(size_t)j * (2 * H) + H + k];
    float4 x0 = *reinterpret_cast<const float4*>(src);
    float4 x1 = *reinterpret_cast<const float4*>(src + 4);
    float xs[8] = {x0.x, x0.y, x0.z, x0.w, x1.x, x1.y, x1.z, x1.w};
    union { short8v v; unsigned short u[8]; } hi, lo;
    #pragma unroll
    for (int i = 0; i < 8; ++i) split2(xs[i], hi.u[i], lo.u[i]);
    *reinterpret_cast<short8v*>(&Wh[e0]) = hi.v;
    *reinterpret_cast<short8v*>(&Wl[e0]) = lo.v;
}

// ---------------------------------------------------------------------------
// K0: build xprevT[k][b]
// ---------------------------------------------------------------------------
__global__ __launch_bounds__(256) void k_build(const int* __restrict__ inp,
                                               const float* __restrict__ loc,
                                               const float* __restrict__ hprev,
                                               const float* __restrict__ emb,
                                               float* __restrict__ xprevT) {
    int gid = blockIdx.x * 256 + threadIdx.x;
    int k = gid >> 6, b = gid & 63;
    float v;
    if (k < 256)      v = emb[(size_t)inp[b] * E + k];
    else if (k < 768) v = loc[b * H + (k - 256)];
    else              v = hprev[b * H + (k - 768)];
    xprevT[gid] = v;
}

// ---------------------------------------------------------------------------
// K1: LSTM cell (fp32)
// ---------------------------------------------------------------------------
__global__ __launch_bounds__(256) void k_lstm(const float* __restrict__ W_ih,
                                              const float* __restrict__ W_hh,
                                              const float* __restrict__ b_ih,
                                              const float* __restrict__ b_hh,
                                              const float* __restrict__ xprevT,
                                              const float* __restrict__ cprev,
                                              float* __restrict__ h_out,
                                              float* __restrict__ c_out,
                                              float* __restrict__ hnewT) {
    int u = blockIdx.x;
    int w = threadIdx.x >> 6;
    int b = threadIdx.x & 63;
    int j = w * 512 + u;
    float a0 = 0.f, a1 = 0.f, a2 = 0.f, a3 = 0.f;
    const float* Wr = &W_ih[(size_t)j * KX];
    for (int k = 0; k < KX; k += 4) {
        float4 wv = *reinterpret_cast<const float4*>(&Wr[k]);
        a0 += wv.x * xprevT[(k + 0) * 64 + b];
        a1 += wv.y * xprevT[(k + 1) * 64 + b];
        a2 += wv.z * xprevT[(k + 2) * 64 + b];
        a3 += wv.w * xprevT[(k + 3) * 64 + b];
    }
    const float* Wr2 = &W_hh[(size_t)j * H];
    const float* hT = &xprevT[KX * 64];
    for (int k = 0; k < H; k += 4) {
        float4 wv = *reinterpret_cast<const float4*>(&Wr2[k]);
        a0 += wv.x * hT[(k + 0) * 64 + b];
        a1 += wv.y * hT[(k + 1) * 64 + b];
        a2 += wv.z * hT[(k + 2) * 64 + b];
        a3 += wv.w * hT[(k + 3) * 64 + b];
    }
    float acc = b_ih[j] + b_hh[j] + ((a0 + a1) + (a2 + a3));
    __shared__ float gs[4][64];
    gs[w][b] = acc;
    __syncthreads();
    if (threadIdx.x < 64) {
        float ig = 1.f / (1.f + __expf(-gs[0][b]));
        float fg = 1.f / (1.f + __expf(-gs[1][b]));
        float gg = tanhf(gs[2][b]);
        float og = 1.f / (1.f + __expf(-gs[3][b]));
        float c = fg * cprev[b * H + u] + ig * gg;
        float h = og * tanhf(c);
        c_out[b * H + u] = c;
        h_out[b * H + u] = h;
        hnewT[u * 64 + b] = h;
    }
}

// ---------------------------------------------------------------------------
// K2: hW_jb[j][b] = b_attn[j] + sum_k h[b][k] * W_attn[j][k]
// ---------------------------------------------------------------------------
__global__ __launch_bounds__(256) void k_hw(const float* __restrict__ W_attn,
                                            const float* __restrict__ b_attn,
                                            const float* __restrict__ hT,
                                            float* __restrict__ hW_jb) {
    int j = blockIdx.x * 4 + (threadIdx.x >> 6);
    int b = threadIdx.x & 63;
    float a0 = 0.f, a1 = 0.f, a2 = 0.f, a3 = 0.f;
    const float* Wr = &W_attn[(size_t)j * (2 * H)];
    for (int k = 0; k < H; k += 4) {
        float4 wv = *reinterpret_cast<const float4*>(&Wr[k]);
        a0 += wv.x * hT[(k + 0) * 64 + b];
        a1 += wv.y * hT[(k + 1) * 64 + b];
        a2 += wv.z * hT[(k + 2) * 64 + b];
        a3 += wv.w * hT[(k + 3) * 64 + b];
    }
    hW_jb[j * 64 + b] = b_attn[j] + ((a0 + a1) + (a2 + a3));
}

// ---------------------------------------------------------------------------
// K3: energy GEMM. A = enc fp32, truncation-split in-kernel at stage time;
// B = prestaged Wh/Wl.  grid 2048 = (mt 0..511) x (jt 0..3), 128x128 tile.
// Reg-prefetch next K-tile after the stage barrier.
// Output: partial_e[jt][m] = sum_{j in tile} tanh(C+hW)*beta.
// ---------------------------------------------------------------------------
#define BKE 32
#define PITCH 40

__global__ __launch_bounds__(256, 3) void k_energy_v3(
        const float* __restrict__ enc,
        const unsigned short* __restrict__ Wh,
        const unsigned short* __restrict__ Wl,
        const float* __restrict__ hW,
        const float* __restrict__ beta,
        float* __restrict__ partial_e) {
    __shared__ unsigned short Ah[128 * PITCH];
    __shared__ unsigned short Al[128 * PITCH];
    __shared__ unsigned short Bh[128 * PITCH];
    __shared__ unsigned short Bl[128 * PITCH];
    __shared__ float red[2][128];

    const int tid  = threadIdx.x;
    const int lane = tid & 63;
    const int wave = tid >> 6;
    const int wm = wave >> 1;
    const int wn = wave & 1;
    const int mt = blockIdx.x >> 2;
    const int jt = blockIdx.x & 3;
    const int m0 = mt * 128;
    const int j0 = jt * 128;

    const int srow = tid >> 2;          // 0..63
    const int skc  = tid & 3;           // 0..3 (8-elem chunk)

    float4 ra0[2], ra1[2];              // next A tile (fp32)
    short8v rb_h[2], rb_l[2];           // next B tile (bf16 hi/lo)
    #pragma unroll
    for (int p = 0; p < 2; ++p) {
        int row = p * 64 + srow;
        const float* asrc = &enc[(size_t)(m0 + row) * H + skc * 8];
        ra0[p] = *reinterpret_cast<const float4*>(asrc);
        ra1[p] = *reinterpret_cast<const float4*>(asrc + 4);
        size_t bo = (size_t)(j0 + row) * H + skc * 8;
        rb_h[p] = *reinterpret_cast<const short8v*>(&Wh[bo]);
        rb_l[p] = *reinterpret_cast<const short8v*>(&Wl[bo]);
    }

    f32x4 acc[4][4];
    #pragma unroll
    for (int i = 0; i < 4; ++i)
        #pragma unroll
        for (int j = 0; j < 4; ++j) acc[i][j] = (f32x4){0.f, 0.f, 0.f, 0.f};

    for (int k0 = 0; k0 < H; k0 += BKE) {
        __syncthreads();                 // previous iter's reads done
        #pragma unroll
        for (int p = 0; p < 2; ++p) {
            float xs[8] = {ra0[p].x, ra0[p].y, ra0[p].z, ra0[p].w,
                           ra1[p].x, ra1[p].y, ra1[p].z, ra1[p].w};
            union { short8v v; unsigned short u[8]; } hi, lo;
            #pragma unroll
            for (int i = 0; i < 8; ++i) split2(xs[i], hi.u[i], lo.u[i]);
            int off = (p * 64 + srow) * PITCH + skc * 8;
            *reinterpret_cast<short8v*>(&Ah[off]) = hi.v;
            *reinterpret_cast<short8v*>(&Al[off]) = lo.v;
            *reinterpret_cast<short8v*>(&Bh[off]) = rb_h[p];
            *reinterpret_cast<short8v*>(&Bl[off]) = rb_l[p];
        }
        __syncthreads();                 // writes visible
        if (k0 + BKE < H) {              // prefetch next tile under the MFMAs
            int kn = k0 + BKE;
            #pragma unroll
            for (int p = 0; p < 2; ++p) {
                int row = p * 64 + srow;
                const float* asrc = &enc[(size_t)(m0 + row) * H + kn + skc * 8];
                ra0[p] = *reinterpret_cast<const float4*>(asrc);
                ra1[p] = *reinterpret_cast<const float4*>(asrc + 4);
                size_t bo = (size_t)(j0 + row) * H + kn + skc * 8;
                rb_h[p] = *reinterpret_cast<const short8v*>(&Wh[bo]);
                rb_l[p] = *reinterpret_cast<const short8v*>(&Wl[bo]);
            }
        }
        const int fr = lane & 15;
        const int kb = (lane >> 4) * 8;
        short8v a_h[4], a_l[4], b_h[4], b_l[4];
        #pragma unroll
        for (int mf = 0; mf < 4; ++mf) {
            int off = (wm * 64 + mf * 16 + fr) * PITCH + kb;
            a_h[mf] = *reinterpret_cast<const short8v*>(&Ah[off]);
            a_l[mf] = *reinterpret_cast<const short8v*>(&Al[off]);
        }
        #pragma unroll
        for (int nf = 0; nf < 4; ++nf) {
            int off = (wn * 64 + nf * 16 + fr) * PITCH + kb;
            b_h[nf] = *reinterpret_cast<const short8v*>(&Bh[off]);
            b_l[nf] = *reinterpret_cast<const short8v*>(&Bl[off]);
        }
        #pragma unroll
        for (int mf = 0; mf < 4; ++mf)
            #pragma unroll
            for (int nf = 0; nf < 4; ++nf) {
                acc[mf][nf] = __builtin_amdgcn_mfma_f32_16x16x32_bf16(
                    a_h[mf], b_h[nf], acc[mf][nf], 0, 0, 0);
                acc[mf][nf] = __builtin_amdgcn_mfma_f32_16x16x32_bf16(
                    a_h[mf], b_l[nf], acc[mf][nf], 0, 0, 0);
                acc[mf][nf] = __builtin_amdgcn_mfma_f32_16x16x32_bf16(
                    a_l[mf], b_h[nf], acc[mf][nf], 0, 0, 0);
            }
    }
    // epilogue: psum[mf][r] = sum_j tanh(C + hW)*beta
    float psum[4][4];
    #pragma unroll
    for (int i = 0; i < 4; ++i)
        #pragma unroll
        for (int r = 0; r < 4; ++r) psum[i][r] = 0.f;
    #pragma unroll
    for (int nf = 0; nf < 4; ++nf) {
        int jj = j0 + wn * 64 + nf * 16 + (lane & 15);
        float bet = beta[jj];
        #pragma unroll
        for (int mf = 0; mf < 4; ++mf) {
            int b_base = (wm * 64 + mf * 16 + (lane >> 4) * 4) & 63;
            float4 hw4 = *reinterpret_cast<const float4*>(&hW[jj * 64 + b_base]);
            float hwv[4] = {hw4.x, hw4.y, hw4.z, hw4.w};
            #pragma unroll
            for (int r = 0; r < 4; ++r) {
                float e = acc[mf][nf][r] + hwv[r];
                float ex = __expf(2.f * e);
                psum[mf][r] += bet * (1.f - 2.f / (ex + 1.f));
            }
        }
    }
    #pragma unroll
    for (int mf = 0; mf < 4; ++mf)
        #pragma unroll
        for (int r = 0; r < 4; ++r) {
            float v = psum[mf][r];
            v += __shfl_xor(v, 1);
            v += __shfl_xor(v, 2);
            v += __shfl_xor(v, 4);
            v += __shfl_xor(v, 8);
            psum[mf][r] = v;
        }
    __syncthreads();
    if ((lane & 15) == 0) {
        #pragma unroll
        for (int mf = 0; mf < 4; ++mf)
            #pragma unroll
            for (int r = 0; r < 4; ++r)
                red[wn][wm * 64 + mf * 16 + (lane >> 4) * 4 + r] = psum[mf][r];
    }
    __syncthreads();
    if (tid < 128)
        partial_e[(size_t)jt * M_TOT + m0 + tid] = red[0][tid] + red[1][tid];
}

// ---------------------------------------------------------------------------
// K4: softmax over l per b.  e[l] = sum_{nb<4} partial_e[nb][l*64+b]
// ---------------------------------------------------------------------------
__global__ __launch_bounds__(256) void k_softmax_l(const float* __restrict__ partial_e,
                                                   float* __restrict__ attn_w) {
    int b = blockIdx.x;
    int tid = threadIdx.x;
    float el[4];
    float m = -1e30f;
    #pragma unroll
    for (int i = 0; i < 4; ++i) {
        int l = i * 256 + tid;
        float e = 0.f;
        #pragma unroll
        for (int nb = 0; nb < 4; ++nb)
            e += partial_e[(size_t)nb * M_TOT + l * 64 + b];
        el[i] = e;
        m = fmaxf(m, e);
    }
    #pragma unroll
    for (int s = 1; s < 64; s <<= 1) m = fmaxf(m, __shfl_xor(m, s));
    __shared__ float redm[4];
    if ((tid & 63) == 0) redm[tid >> 6] = m;
    __syncthreads();
    m = fmaxf(fmaxf(redm[0], redm[1]), fmaxf(redm[2], redm[3]));
    float s = 0.f;
    #pragma unroll
    for (int i = 0; i < 4; ++i) { el[i] = __expf(el[i] - m); s += el[i]; }
    #pragma unroll
    for (int sh = 1; sh < 64; sh <<= 1) s += __shfl_xor(s, sh);
    __shared__ float reds[4];
    if ((tid & 63) == 0) reds[tid >> 6] = s;
    __syncthreads();
    s = reds[0] + reds[1] + reds[2] + reds[3];
    float inv = 1.f / s;
    #pragma unroll
    for (int i = 0; i < 4; ++i)
        attn_w[(i * 256 + tid) * 64 + b] = el[i] * inv;
}

// ---------------------------------------------------------------------------
// K5: context partials over l chunks.
// ---------------------------------------------------------------------------
__global__ __launch_bounds__(256) void k_ctx_part(const float* __restrict__ attn_w,
                                                  const float* __restrict__ enc,
                                                  float* __restrict__ ctx_part) {
    int chunk = blockIdx.x, b = blockIdx.y;
    int h = threadIdx.x * 2;
    float2 acc = {0.f, 0.f};
    for (int i = 0; i < 32; ++i) {
        int l = chunk * 32 + i;
        float w = attn_w[l * 64 + b];
        float2 e2 = *reinterpret_cast<const float2*>(
            &enc[((size_t)l * 64 + b) * H + h]);
        acc.x += w * e2.x;
        acc.y += w * e2.y;
    }
    *reinterpret_cast<float2*>(&ctx_part[((size_t)(chunk * 64 + b)) * H + h]) = acc;
}

__global__ __launch_bounds__(256) void k_ctx_reduce(const float* __restrict__ ctx_part,
                                                    float* __restrict__ ctxT) {
    int gid = blockIdx.x * 256 + threadIdx.x;
    int b = gid >> 9, h = gid & 511;
    float s = 0.f;
    for (int c = 0; c < 32; ++c)
        s += ctx_part[((size_t)(c * 64 + b)) * H + h];
    ctxT[h * 64 + b] = s;
}

// ---------------------------------------------------------------------------
// K6: co[b][j] = tanh([h | ctx] . W_oc[j] + b_oc[j])
// ---------------------------------------------------------------------------
__global__ __launch_bounds__(256) void k_co(const float* __restrict__ W_oc,
                                            const float* __restrict__ b_oc,
                                            const float* __restrict__ hT,
                                            const float* __restrict__ ctxT,
                                            float* __restrict__ co_out) {
    int j = blockIdx.x * 4 + (threadIdx.x >> 6);
    int b = threadIdx.x & 63;
    float a0 = 0.f, a1 = 0.f, a2 = 0.f, a3 = 0.f;
    const float* Wr = &W_oc[(size_t)j * (2 * H)];
    for (int k = 0; k < H; k += 4) {
        float4 wv = *reinterpret_cast<const float4*>(&Wr[k]);
        a0 += wv.x * hT[(k + 0) * 64 + b];
        a1 += wv.y * hT[(k + 1) * 64 + b];
        a2 += wv.z * hT[(k + 2) * 64 + b];
        a3 += wv.w * hT[(k + 3) * 64 + b];
    }
    const float* Wr2 = Wr + H;
    for (int k = 0; k < H; k += 4) {
        float4 wv = *reinterpret_cast<const float4*>(&Wr2[k]);
        a0 += wv.x * ctxT[(k + 0) * 64 + b];
        a1 += wv.y * ctxT[(k + 1) * 64 + b];
        a2 += wv.z * ctxT[(k + 2) * 64 + b];
        a3 += wv.w * ctxT[(k + 3) * 64 + b];
    }
    co_out[b * H + j] = tanhf(b_oc[j] + ((a0 + a1) + (a2 + a3)));
}

// ---------------------------------------------------------------------------
// K7: logits GEMM via in-kernel truncation-split MFMA.
// grid 500 (j-tiles of 64).  M=64 (batch), K=512, BK=32.
// A = co (L2-resident, split per block), B = W_out rows (streamed, split).
// ---------------------------------------------------------------------------
__global__ __launch_bounds__(256) void k_logits_mfma(const float* __restrict__ co,
                                                     const float* __restrict__ W_out,
                                                     const float* __restrict__ b_out,
                                                     float* __restrict__ logits) {
    __shared__ unsigned short Ah[64 * PITCH];
    __shared__ unsigned short Al[64 * PITCH];
    __shared__ unsigned short Bh[64 * PITCH];
    __shared__ unsigned short Bl[64 * PITCH];

    const int tid  = threadIdx.x;
    const int lane = tid & 63;
    const int wave = tid >> 6;
    const int wm = wave >> 1;           // 0..1 : m-half (32 rows)
    const int wn = wave & 1;            // 0..1 : j-half (32 cols)
    const int j0 = blockIdx.x * 64;

    const int srow = tid >> 2;          // 0..63
    const int skc  = tid & 3;           // 0..3

    float4 ra0, ra1, rb0, rb1;
    {
        const float* as = &co[(size_t)srow * H + skc * 8];
        ra0 = *reinterpret_cast<const float4*>(as);
        ra1 = *reinterpret_cast<const float4*>(as + 4);
        const float* bs = &W_out[(size_t)(j0 + srow) * H + skc * 8];
        rb0 = *reinterpret_cast<const float4*>(bs);
        rb1 = *reinterpret_cast<const float4*>(bs + 4);
    }

    f32x4 acc[2][2];
    #pragma unroll
    for (int i = 0; i < 2; ++i)
        #pragma unroll
        for (int j = 0; j < 2; ++j) acc[i][j] = (f32x4){0.f, 0.f, 0.f, 0.f};

    for (int k0 = 0; k0 < H; k0 += BKE) {
        __syncthreads();
        {
            float xs[8] = {ra0.x, ra0.y, ra0.z, ra0.w, ra1.x, ra1.y, ra1.z, ra1.w};
            union { short8v v; unsigned short u[8]; } hi, lo;
            #pragma unroll
            for (int i = 0; i < 8; ++i) split2(xs[i], hi.u[i], lo.u[i]);
            int off = srow * PITCH + skc * 8;
            *reinterpret_cast<short8v*>(&Ah[off]) = hi.v;
            *reinterpret_cast<short8v*>(&Al[off]) = lo.v;
            float ys[8] = {rb0.x, rb0.y, rb0.z, rb0.w, rb1.x, rb1.y, rb1.z, rb1.w};
            union { short8v v; unsigned short u[8]; } hib, lob;
            #pragma unroll
            for (int i = 0; i < 8; ++i) split2(ys[i], hib.u[i], lob.u[i]);
            *reinterpret_cast<short8v*>(&Bh[off]) = hib.v;
            *reinterpret_cast<short8v*>(&Bl[off]) = lob.v;
        }
        __syncthreads();
        if (k0 + BKE < H) {
            int kn = k0 + BKE;
            const float* as = &co[(size_t)srow * H + kn + skc * 8];
            ra0 = *reinterpret_cast<const float4*>(as);
            ra1 = *reinterpret_cast<const float4*>(as + 4);
            const float* bs = &W_out[(size_t)(j0 + srow) * H + kn + skc * 8];
            rb0 = *reinterpret_cast<const float4*>(bs);
            rb1 = *reinterpret_cast<const float4*>(bs + 4);
        }
        const int fr = lane & 15;
        const int kb = (lane >> 4) * 8;
        short8v a_h[2], a_l[2], b_h[2], b_l[2];
        #pragma unroll
        for (int mf = 0; mf < 2; ++mf) {
            int off = (wm * 32 + mf * 16 + fr) * PITCH + kb;
            a_h[mf] = *reinterpret_cast<const short8v*>(&Ah[off]);
            a_l[mf] = *reinterpret_cast<const short8v*>(&Al[off]);
        }
        #pragma unroll
        for (int nf = 0; nf < 2; ++nf) {
            int off = (wn * 32 + nf * 16 + fr) * PITCH + kb;
            b_h[nf] = *reinterpret_cast<const short8v*>(&Bh[off]);
            b_l[nf] = *reinterpret_cast<const short8v*>(&Bl[off]);
        }
        #pragma unroll
        for (int mf = 0; mf < 2; ++mf)
            #pragma unroll
            for (int nf = 0; nf < 2; ++nf) {
                acc[mf][nf] = __builtin_amdgcn_mfma_f32_16x16x32_bf16(
                    a_h[mf], b_h[nf], acc[mf][nf], 0, 0, 0);
                acc[mf][nf] = __builtin_amdgcn_mfma_f32_16x16x32_bf16(
                    a_h[mf], b_l[nf], acc[mf][nf], 0, 0, 0);
                acc[mf][nf] = __builtin_amdgcn_mfma_f32_16x16x32_bf16(
                    a_l[mf], b_h[nf], acc[mf][nf], 0, 0, 0);
            }
    }
    #pragma unroll
    for (int nf = 0; nf < 2; ++nf) {
        int j = j0 + wn * 32 + nf * 16 + (lane & 15);
        float bo = b_out[j];
        #pragma unroll
        for (int mf = 0; mf < 2; ++mf) {
            int mbase = wm * 32 + mf * 16 + (lane >> 4) * 4;
            #pragma unroll
            for (int r = 0; r < 4; ++r)
                logits[(size_t)(mbase + r) * V + j] = acc[mf][nf][r] + bo;
        }
    }
}

// ---------------------------------------------------------------------------
// K8: log_softmax per b over V.
// ---------------------------------------------------------------------------
__global__ __launch_bounds__(1024) void k_logsm(const float* __restrict__ logits,
                                                float* __restrict__ out) {
    int b = blockIdx.x;
    int tid = threadIdx.x;
    const float* row = &logits[(size_t)b * V];
    float m = -1e30f;
    for (int i = tid; i < V; i += 1024) m = fmaxf(m, row[i]);
    #pragma unroll
    for (int s = 1; s < 64; s <<= 1) m = fmaxf(m, __shfl_xor(m, s));
    __shared__ float redm[16];
    if ((tid & 63) == 0) redm[tid >> 6] = m;
    __syncthreads();
    m = redm[0];
    #pragma unroll
    for (int i = 1; i < 16; ++i) m = fmaxf(m, redm[i]);
    float s = 0.f;
    for (int i = tid; i < V; i += 1024) s += __expf(row[i] - m);
    #pragma unroll
    for (int sh = 1; sh < 64; sh <<= 1) s += __shfl_xor(s, sh);
    __shared__ float reds[16];
    if ((tid & 63) == 0) reds[tid >> 6] = s;
    __syncthreads();
    s = reds[0];
    #pragma unroll
    for (int i = 1; i < 16; ++i) s += reds[i];
    float lse = m + __logf(s);
    for (int i = tid; i < V; i += 1024)
        out[(size_t)b * V + i] = row[i] - lse;
}

// ---------------------------------------------------------------------------
extern "C" void kernel_launch(void* const* d_in, const int* in_sizes, int n_in,
                              void* d_out, int out_size, void* d_ws, size_t ws_size,
                              hipStream_t stream) {
    const int*   inp    = (const int*)  d_in[0];
    const float* loc    = (const float*)d_in[1];
    const float* hprev  = (const float*)d_in[2];
    const float* cprev  = (const float*)d_in[3];
    const float* enc    = (const float*)d_in[4];
    const float* emb    = (const float*)d_in[5];
    const float* W_ih   = (const float*)d_in[6];
    const float* W_hh   = (const float*)d_in[7];
    const float* b_ih   = (const float*)d_in[8];
    const float* b_hh   = (const float*)d_in[9];
    const float* W_attn = (const float*)d_in[10];
    const float* b_attn = (const float*)d_in[11];
    const float* beta   = (const float*)d_in[12];
    const float* W_oc   = (const float*)d_in[13];
    const float* b_oc   = (const float*)d_in[14];
    const float* W_out  = (const float*)d_in[15];
    const float* b_out  = (const float*)d_in[16];

    float* out = (float*)d_out;
    float* out_co = out + (size_t)B * V;
    float* out_h  = out_co + B * H;
    float* out_c  = out_h  + B * H;

    float* ws = (float*)d_ws;
    float* xprevT = ws;                                  //    81920
    float* hnewT  = xprevT + 1280 * 64;                  //    32768
    float* hW     = hnewT  + H * 64;                     //    32768
    float* pe     = hW     + H * 64;                     //  4*65536
    float* attnw  = pe     + 4 * M_TOT;                  //    65536
    float* ctxp   = attnw  + M_TOT;                      //  1048576
    float* ctxT   = ctxp   + 32 * 64 * H;                //    32768
    float* logits = ctxT   + H * 64;                     //  2048000
    float* ws_end = logits + (size_t)B * V;              // = ws + 3604480
    unsigned short* Wh = (unsigned short*)ws_end;        // 262144 u16
    unsigned short* Wl = Wh + H * H;

    k_split_w<<<128, 256, 0, stream>>>(W_attn, Wh, Wl);
    k_build <<<320, 256, 0, stream>>>(inp, loc, hprev, emb, xprevT);
    k_lstm  <<<512, 256, 0, stream>>>(W_ih, W_hh, b_ih, b_hh, xprevT, cprev,
                                      out_h, out_c, hnewT);
    k_hw    <<<128, 256, 0, stream>>>(W_attn, b_attn, hnewT, hW);
    k_energy_v3<<<2048, 256, 0, stream>>>(enc, Wh, Wl, hW, beta, pe);
    k_softmax_l<<<64, 256, 0, stream>>>(pe, attnw);
    k_ctx_part <<<dim3(32, 64), 256, 0, stream>>>(attnw, enc, ctxp);
    k_ctx_reduce<<<128, 256, 0, stream>>>(ctxp, ctxT);
    k_co    <<<128, 256, 0, stream>>>(W_oc, b_oc, hnewT, ctxT, out_co);
    k_logits_mfma<<<500, 256, 0, stream>>>(out_co, W_out, b_out, logits);
    k_logsm <<<64, 1024, 0, stream>>>(logits, out);
}

// Round 6
// 257.097 us; speedup vs baseline: 1.4317x; 1.1229x over previous
//
#include <hip/hip_runtime.h>
#include <hip/hip_bf16.h>
#include <cstddef>

// Problem dims
#define H   512
#define E   256
#define V   32000
#define L   1024
#define B   64
#define KX  768      // E + H
#define M_TOT 65536  // L*B

typedef __attribute__((ext_vector_type(8))) _Float16 half8v;
typedef __attribute__((ext_vector_type(4))) float f32x4;

// ---------------------------------------------------------------------------
// K-1: convert W_attn[:, H:] to fp16 once (512 KB out).
// ---------------------------------------------------------------------------
__global__ __launch_bounds__(256) void k_conv_w(const float* __restrict__ W_attn,
                                                unsigned short* __restrict__ Wf) {
    int e0 = blockIdx.x * 2048 + threadIdx.x * 8;      // 0..262143
    int j = e0 >> 9, k = e0 & 511;
    const float* src = &W_attn[(size_t)j * (2 * H) + H + k];
    float4 x0 = *reinterpret_cast<const float4*>(src);
    float4 x1 = *reinterpret_cast<const float4*>(src + 4);
    float xs[8] = {x0.x, x0.y, x0.z, x0.w, x1.x, x1.y, x1.z, x1.w};
    union { half8v v; _Float16 u[8]; } hv;
    #pragma unroll
    for (int i = 0; i < 8; ++i) hv.u[i] = (_Float16)xs[i];
    *reinterpret_cast<half8v*>(&Wf[e0]) = hv.v;
}

// ---------------------------------------------------------------------------
// K0: build xprevT[k][b]
// ---------------------------------------------------------------------------
__global__ __launch_bounds__(256) void k_build(const int* __restrict__ inp,
                                               const float* __restrict__ loc,
                                               const float* __restrict__ hprev,
                                               const float* __restrict__ emb,
                                               float* __restrict__ xprevT) {
    int gid = blockIdx.x * 256 + threadIdx.x;
    int k = gid >> 6, b = gid & 63;
    float v;
    if (k < 256)      v = emb[(size_t)inp[b] * E + k];
    else if (k < 768) v = loc[b * H + (k - 256)];
    else              v = hprev[b * H + (k - 768)];
    xprevT[gid] = v;
}

// ---------------------------------------------------------------------------
// K1: LSTM cell (fp32)
// ---------------------------------------------------------------------------
__global__ __launch_bounds__(256) void k_lstm(const float* __restrict__ W_ih,
                                              const float* __restrict__ W_hh,
                                              const float* __restrict__ b_ih,
                                              const float* __restrict__ b_hh,
                                              const float* __restrict__ xprevT,
                                              const float* __restrict__ cprev,
                                              float* __restrict__ h_out,
                                              float* __restrict__ c_out,
                                              float* __restrict__ hnewT) {
    int u = blockIdx.x;
    int w = threadIdx.x >> 6;
    int b = threadIdx.x & 63;
    int j = w * 512 + u;
    float a0 = 0.f, a1 = 0.f, a2 = 0.f, a3 = 0.f;
    const float* Wr = &W_ih[(size_t)j * KX];
    for (int k = 0; k < KX; k += 4) {
        float4 wv = *reinterpret_cast<const float4*>(&Wr[k]);
        a0 += wv.x * xprevT[(k + 0) * 64 + b];
        a1 += wv.y * xprevT[(k + 1) * 64 + b];
        a2 += wv.z * xprevT[(k + 2) * 64 + b];
        a3 += wv.w * xprevT[(k + 3) * 64 + b];
    }
    const float* Wr2 = &W_hh[(size_t)j * H];
    const float* hT = &xprevT[KX * 64];
    for (int k = 0; k < H; k += 4) {
        float4 wv = *reinterpret_cast<const float4*>(&Wr2[k]);
        a0 += wv.x * hT[(k + 0) * 64 + b];
        a1 += wv.y * hT[(k + 1) * 64 + b];
        a2 += wv.z * hT[(k + 2) * 64 + b];
        a3 += wv.w * hT[(k + 3) * 64 + b];
    }
    float acc = b_ih[j] + b_hh[j] + ((a0 + a1) + (a2 + a3));
    __shared__ float gs[4][64];
    gs[w][b] = acc;
    __syncthreads();
    if (threadIdx.x < 64) {
        float ig = 1.f / (1.f + __expf(-gs[0][b]));
        float fg = 1.f / (1.f + __expf(-gs[1][b]));
        float gg = tanhf(gs[2][b]);
        float og = 1.f / (1.f + __expf(-gs[3][b]));
        float c = fg * cprev[b * H + u] + ig * gg;
        float h = og * tanhf(c);
        c_out[b * H + u] = c;
        h_out[b * H + u] = h;
        hnewT[u * 64 + b] = h;
    }
}

// ---------------------------------------------------------------------------
// K2: hW_jb[j][b] = b_attn[j] + sum_k h[b][k] * W_attn[j][k]
// ---------------------------------------------------------------------------
__global__ __launch_bounds__(256) void k_hw(const float* __restrict__ W_attn,
                                            const float* __restrict__ b_attn,
                                            const float* __restrict__ hT,
                                            float* __restrict__ hW_jb) {
    int j = blockIdx.x * 4 + (threadIdx.x >> 6);
    int b = threadIdx.x & 63;
    float a0 = 0.f, a1 = 0.f, a2 = 0.f, a3 = 0.f;
    const float* Wr = &W_attn[(size_t)j * (2 * H)];
    for (int k = 0; k < H; k += 4) {
        float4 wv = *reinterpret_cast<const float4*>(&Wr[k]);
        a0 += wv.x * hT[(k + 0) * 64 + b];
        a1 += wv.y * hT[(k + 1) * 64 + b];
        a2 += wv.z * hT[(k + 2) * 64 + b];
        a3 += wv.w * hT[(k + 3) * 64 + b];
    }
    hW_jb[j * 64 + b] = b_attn[j] + ((a0 + a1) + (a2 + a3));
}

// ---------------------------------------------------------------------------
// K3: energy GEMM, pure fp16 single-MFMA.
// A = enc fp32 -> fp16 at stage; B = prestaged fp16.
// grid 2048 = (mt 0..511) x (jt 0..3), 128x128 tile, BK=32.
// Output: partial_e[jt][m] = sum_{j in tile} tanh(C+hW)*beta.
// ---------------------------------------------------------------------------
#define BKE 32
#define PITCH 40

__global__ __launch_bounds__(256, 4) void k_energy_v4(
        const float* __restrict__ enc,
        const unsigned short* __restrict__ Wf,
        const float* __restrict__ hW,
        const float* __restrict__ beta,
        float* __restrict__ partial_e) {
    __shared__ unsigned short Ah[128 * PITCH];
    __shared__ unsigned short Bh[128 * PITCH];
    __shared__ float red[2][128];

    const int tid  = threadIdx.x;
    const int lane = tid & 63;
    const int wave = tid >> 6;
    const int wm = wave >> 1;
    const int wn = wave & 1;
    const int mt = blockIdx.x >> 2;
    const int jt = blockIdx.x & 3;
    const int m0 = mt * 128;
    const int j0 = jt * 128;

    const int srow = tid >> 2;          // 0..63
    const int skc  = tid & 3;           // 0..3 (8-elem chunk)

    float4 ra0[2], ra1[2];              // next A tile (fp32)
    half8v rb[2];                       // next B tile (fp16)
    #pragma unroll
    for (int p = 0; p < 2; ++p) {
        int row = p * 64 + srow;
        const float* asrc = &enc[(size_t)(m0 + row) * H + skc * 8];
        ra0[p] = *reinterpret_cast<const float4*>(asrc);
        ra1[p] = *reinterpret_cast<const float4*>(asrc + 4);
        rb[p] = *reinterpret_cast<const half8v*>(&Wf[(size_t)(j0 + row) * H + skc * 8]);
    }

    f32x4 acc[4][4];
    #pragma unroll
    for (int i = 0; i < 4; ++i)
        #pragma unroll
        for (int j = 0; j < 4; ++j) acc[i][j] = (f32x4){0.f, 0.f, 0.f, 0.f};

    for (int k0 = 0; k0 < H; k0 += BKE) {
        __syncthreads();                 // previous iter's reads done
        #pragma unroll
        for (int p = 0; p < 2; ++p) {
            float xs[8] = {ra0[p].x, ra0[p].y, ra0[p].z, ra0[p].w,
                           ra1[p].x, ra1[p].y, ra1[p].z, ra1[p].w};
            union { half8v v; _Float16 u[8]; } hv;
            #pragma unroll
            for (int i = 0; i < 8; ++i) hv.u[i] = (_Float16)xs[i];
            int off = (p * 64 + srow) * PITCH + skc * 8;
            *reinterpret_cast<half8v*>(&Ah[off]) = hv.v;
            *reinterpret_cast<half8v*>(&Bh[off]) = rb[p];
        }
        __syncthreads();                 // writes visible
        if (k0 + BKE < H) {              // prefetch next tile under the MFMAs
            int kn = k0 + BKE;
            #pragma unroll
            for (int p = 0; p < 2; ++p) {
                int row = p * 64 + srow;
                const float* asrc = &enc[(size_t)(m0 + row) * H + kn + skc * 8];
                ra0[p] = *reinterpret_cast<const float4*>(asrc);
                ra1[p] = *reinterpret_cast<const float4*>(asrc + 4);
                rb[p] = *reinterpret_cast<const half8v*>(&Wf[(size_t)(j0 + row) * H + kn + skc * 8]);
            }
        }
        const int fr = lane & 15;
        const int kb = (lane >> 4) * 8;
        half8v a_h[4], b_h[4];
        #pragma unroll
        for (int mf = 0; mf < 4; ++mf) {
            int off = (wm * 64 + mf * 16 + fr) * PITCH + kb;
            a_h[mf] = *reinterpret_cast<const half8v*>(&Ah[off]);
        }
        #pragma unroll
        for (int nf = 0; nf < 4; ++nf) {
            int off = (wn * 64 + nf * 16 + fr) * PITCH + kb;
            b_h[nf] = *reinterpret_cast<const half8v*>(&Bh[off]);
        }
        #pragma unroll
        for (int mf = 0; mf < 4; ++mf)
            #pragma unroll
            for (int nf = 0; nf < 4; ++nf)
                acc[mf][nf] = __builtin_amdgcn_mfma_f32_16x16x32_f16(
                    a_h[mf], b_h[nf], acc[mf][nf], 0, 0, 0);
    }
    // epilogue: psum[mf][r] = sum_j tanh(C + hW)*beta
    float psum[4][4];
    #pragma unroll
    for (int i = 0; i < 4; ++i)
        #pragma unroll
        for (int r = 0; r < 4; ++r) psum[i][r] = 0.f;
    #pragma unroll
    for (int nf = 0; nf < 4; ++nf) {
        int jj = j0 + wn * 64 + nf * 16 + (lane & 15);
        float bet = beta[jj];
        #pragma unroll
        for (int mf = 0; mf < 4; ++mf) {
            int b_base = (wm * 64 + mf * 16 + (lane >> 4) * 4) & 63;
            float4 hw4 = *reinterpret_cast<const float4*>(&hW[jj * 64 + b_base]);
            float hwv[4] = {hw4.x, hw4.y, hw4.z, hw4.w};
            #pragma unroll
            for (int r = 0; r < 4; ++r) {
                float e = acc[mf][nf][r] + hwv[r];
                float ex = __expf(2.f * e);
                psum[mf][r] += bet * (1.f - 2.f / (ex + 1.f));
            }
        }
    }
    #pragma unroll
    for (int mf = 0; mf < 4; ++mf)
        #pragma unroll
        for (int r = 0; r < 4; ++r) {
            float v = psum[mf][r];
            v += __shfl_xor(v, 1);
            v += __shfl_xor(v, 2);
            v += __shfl_xor(v, 4);
            v += __shfl_xor(v, 8);
            psum[mf][r] = v;
        }
    __syncthreads();
    if ((lane & 15) == 0) {
        #pragma unroll
        for (int mf = 0; mf < 4; ++mf)
            #pragma unroll
            for (int r = 0; r < 4; ++r)
                red[wn][wm * 64 + mf * 16 + (lane >> 4) * 4 + r] = psum[mf][r];
    }
    __syncthreads();
    if (tid < 128)
        partial_e[(size_t)jt * M_TOT + m0 + tid] = red[0][tid] + red[1][tid];
}

// ---------------------------------------------------------------------------
// K4: softmax over l per b.  e[l] = sum_{nb<4} partial_e[nb][l*64+b]
// ---------------------------------------------------------------------------
__global__ __launch_bounds__(256) void k_softmax_l(const float* __restrict__ partial_e,
                                                   float* __restrict__ attn_w) {
    int b = blockIdx.x;
    int tid = threadIdx.x;
    float el[4];
    float m = -1e30f;
    #pragma unroll
    for (int i = 0; i < 4; ++i) {
        int l = i * 256 + tid;
        float e = 0.f;
        #pragma unroll
        for (int nb = 0; nb < 4; ++nb)
            e += partial_e[(size_t)nb * M_TOT + l * 64 + b];
        el[i] = e;
        m = fmaxf(m, e);
    }
    #pragma unroll
    for (int s = 1; s < 64; s <<= 1) m = fmaxf(m, __shfl_xor(m, s));
    __shared__ float redm[4];
    if ((tid & 63) == 0) redm[tid >> 6] = m;
    __syncthreads();
    m = fmaxf(fmaxf(redm[0], redm[1]), fmaxf(redm[2], redm[3]));
    float s = 0.f;
    #pragma unroll
    for (int i = 0; i < 4; ++i) { el[i] = __expf(el[i] - m); s += el[i]; }
    #pragma unroll
    for (int sh = 1; sh < 64; sh <<= 1) s += __shfl_xor(s, sh);
    __shared__ float reds[4];
    if ((tid & 63) == 0) reds[tid >> 6] = s;
    __syncthreads();
    s = reds[0] + reds[1] + reds[2] + reds[3];
    float inv = 1.f / s;
    #pragma unroll
    for (int i = 0; i < 4; ++i)
        attn_w[(i * 256 + tid) * 64 + b] = el[i] * inv;
}

// ---------------------------------------------------------------------------
// K5: context partials over l chunks. float4, 128 threads.
// ---------------------------------------------------------------------------
__global__ __launch_bounds__(128) void k_ctx_part(const float* __restrict__ attn_w,
                                                  const float* __restrict__ enc,
                                                  float* __restrict__ ctx_part) {
    int chunk = blockIdx.x, b = blockIdx.y;
    int h = threadIdx.x * 4;
    float4 acc = {0.f, 0.f, 0.f, 0.f};
    for (int i = 0; i < 32; ++i) {
        int l = chunk * 32 + i;
        float w = attn_w[l * 64 + b];
        float4 e4 = *reinterpret_cast<const float4*>(
            &enc[((size_t)l * 64 + b) * H + h]);
        acc.x += w * e4.x;
        acc.y += w * e4.y;
        acc.z += w * e4.z;
        acc.w += w * e4.w;
    }
    *reinterpret_cast<float4*>(&ctx_part[((size_t)(chunk * 64 + b)) * H + h]) = acc;
}

__global__ __launch_bounds__(256) void k_ctx_reduce(const float* __restrict__ ctx_part,
                                                    float* __restrict__ ctxT) {
    int gid = blockIdx.x * 256 + threadIdx.x;
    int b = gid >> 9, h = gid & 511;
    float s = 0.f;
    for (int c = 0; c < 32; ++c)
        s += ctx_part[((size_t)(c * 64 + b)) * H + h];
    ctxT[h * 64 + b] = s;
}

// ---------------------------------------------------------------------------
// K6: co[b][j] = tanh([h | ctx] . W_oc[j] + b_oc[j])
// ---------------------------------------------------------------------------
__global__ __launch_bounds__(256) void k_co(const float* __restrict__ W_oc,
                                            const float* __restrict__ b_oc,
                                            const float* __restrict__ hT,
                                            const float* __restrict__ ctxT,
                                            float* __restrict__ co_out) {
    int j = blockIdx.x * 4 + (threadIdx.x >> 6);
    int b = threadIdx.x & 63;
    float a0 = 0.f, a1 = 0.f, a2 = 0.f, a3 = 0.f;
    const float* Wr = &W_oc[(size_t)j * (2 * H)];
    for (int k = 0; k < H; k += 4) {
        float4 wv = *reinterpret_cast<const float4*>(&Wr[k]);
        a0 += wv.x * hT[(k + 0) * 64 + b];
        a1 += wv.y * hT[(k + 1) * 64 + b];
        a2 += wv.z * hT[(k + 2) * 64 + b];
        a3 += wv.w * hT[(k + 3) * 64 + b];
    }
    const float* Wr2 = Wr + H;
    for (int k = 0; k < H; k += 4) {
        float4 wv = *reinterpret_cast<const float4*>(&Wr2[k]);
        a0 += wv.x * ctxT[(k + 0) * 64 + b];
        a1 += wv.y * ctxT[(k + 1) * 64 + b];
        a2 += wv.z * ctxT[(k + 2) * 64 + b];
        a3 += wv.w * ctxT[(k + 3) * 64 + b];
    }
    co_out[b * H + j] = tanhf(b_oc[j] + ((a0 + a1) + (a2 + a3)));
}

// ---------------------------------------------------------------------------
// K7: logits GEMM, pure fp16 single-MFMA. grid 500 (64-wide j tiles).
// ---------------------------------------------------------------------------
__global__ __launch_bounds__(256) void k_logits_v2(const float* __restrict__ co,
                                                   const float* __restrict__ W_out,
                                                   const float* __restrict__ b_out,
                                                   float* __restrict__ logits) {
    __shared__ unsigned short Ah[64 * PITCH];
    __shared__ unsigned short Bh[64 * PITCH];

    const int tid  = threadIdx.x;
    const int lane = tid & 63;
    const int wave = tid >> 6;
    const int wm = wave >> 1;           // 0..1 : m-half (32 rows)
    const int wn = wave & 1;            // 0..1 : j-half (32 cols)
    const int j0 = blockIdx.x * 64;

    const int srow = tid >> 2;          // 0..63
    const int skc  = tid & 3;           // 0..3

    float4 ra0, ra1, rb0, rb1;
    {
        const float* as = &co[(size_t)srow * H + skc * 8];
        ra0 = *reinterpret_cast<const float4*>(as);
        ra1 = *reinterpret_cast<const float4*>(as + 4);
        const float* bs = &W_out[(size_t)(j0 + srow) * H + skc * 8];
        rb0 = *reinterpret_cast<const float4*>(bs);
        rb1 = *reinterpret_cast<const float4*>(bs + 4);
    }

    f32x4 acc[2][2];
    #pragma unroll
    for (int i = 0; i < 2; ++i)
        #pragma unroll
        for (int j = 0; j < 2; ++j) acc[i][j] = (f32x4){0.f, 0.f, 0.f, 0.f};

    for (int k0 = 0; k0 < H; k0 += BKE) {
        __syncthreads();
        {
            float xs[8] = {ra0.x, ra0.y, ra0.z, ra0.w, ra1.x, ra1.y, ra1.z, ra1.w};
            union { half8v v; _Float16 u[8]; } ha;
            #pragma unroll
            for (int i = 0; i < 8; ++i) ha.u[i] = (_Float16)xs[i];
            float ys[8] = {rb0.x, rb0.y, rb0.z, rb0.w, rb1.x, rb1.y, rb1.z, rb1.w};
            union { half8v v; _Float16 u[8]; } hb;
            #pragma unroll
            for (int i = 0; i < 8; ++i) hb.u[i] = (_Float16)ys[i];
            int off = srow * PITCH + skc * 8;
            *reinterpret_cast<half8v*>(&Ah[off]) = ha.v;
            *reinterpret_cast<half8v*>(&Bh[off]) = hb.v;
        }
        __syncthreads();
        if (k0 + BKE < H) {
            int kn = k0 + BKE;
            const float* as = &co[(size_t)srow * H + kn + skc * 8];
            ra0 = *reinterpret_cast<const float4*>(as);
            ra1 = *reinterpret_cast<const float4*>(as + 4);
            const float* bs = &W_out[(size_t)(j0 + srow) * H + kn + skc * 8];
            rb0 = *reinterpret_cast<const float4*>(bs);
            rb1 = *reinterpret_cast<const float4*>(bs + 4);
        }
        const int fr = lane & 15;
        const int kb = (lane >> 4) * 8;
        half8v a_h[2], b_h[2];
        #pragma unroll
        for (int mf = 0; mf < 2; ++mf) {
            int off = (wm * 32 + mf * 16 + fr) * PITCH + kb;
            a_h[mf] = *reinterpret_cast<const half8v*>(&Ah[off]);
        }
        #pragma unroll
        for (int nf = 0; nf < 2; ++nf) {
            int off = (wn * 32 + nf * 16 + fr) * PITCH + kb;
            b_h[nf] = *reinterpret_cast<const half8v*>(&Bh[off]);
        }
        #pragma unroll
        for (int mf = 0; mf < 2; ++mf)
            #pragma unroll
            for (int nf = 0; nf < 2; ++nf)
                acc[mf][nf] = __builtin_amdgcn_mfma_f32_16x16x32_f16(
                    a_h[mf], b_h[nf], acc[mf][nf], 0, 0, 0);
    }
    #pragma unroll
    for (int nf = 0; nf < 2; ++nf) {
        int j = j0 + wn * 32 + nf * 16 + (lane & 15);
        float bo = b_out[j];
        #pragma unroll
        for (int mf = 0; mf < 2; ++mf) {
            int mbase = wm * 32 + mf * 16 + (lane >> 4) * 4;
            #pragma unroll
            for (int r = 0; r < 4; ++r)
                logits[(size_t)(mbase + r) * V + j] = acc[mf][nf][r] + bo;
        }
    }
}

// ---------------------------------------------------------------------------
// K8a: per-(b, chunk) partial max & expsum. grid (8 chunks, 64 b), 256 thr.
// ---------------------------------------------------------------------------
__global__ __launch_bounds__(256) void k_lsm_part(const float* __restrict__ logits,
                                                  float* __restrict__ pmax,
                                                  float* __restrict__ psum) {
    int chunk = blockIdx.x, b = blockIdx.y;
    int tid = threadIdx.x;
    const float* row = &logits[(size_t)b * V + chunk * 4000];
    float v[16];
    float m = -1e30f;
    #pragma unroll
    for (int t = 0; t < 16; ++t) {
        int i = t * 256 + tid;
        v[t] = (i < 4000) ? row[i] : -1e30f;
        m = fmaxf(m, v[t]);
    }
    #pragma unroll
    for (int s = 1; s < 64; s <<= 1) m = fmaxf(m, __shfl_xor(m, s));
    __shared__ float redm[4];
    if ((tid & 63) == 0) redm[tid >> 6] = m;
    __syncthreads();
    m = fmaxf(fmaxf(redm[0], redm[1]), fmaxf(redm[2], redm[3]));
    float s = 0.f;
    #pragma unroll
    for (int t = 0; t < 16; ++t) s += __expf(v[t] - m);
    #pragma unroll
    for (int sh = 1; sh < 64; sh <<= 1) s += __shfl_xor(s, sh);
    __shared__ float reds[4];
    if ((tid & 63) == 0) reds[tid >> 6] = s;
    __syncthreads();
    if (tid == 0) {
        pmax[chunk * 64 + b] = m;
        psum[chunk * 64 + b] = reds[0] + reds[1] + reds[2] + reds[3];
    }
}

// K8b: lse[b] = gmax + log(sum of rescaled partials). 1 block, 64 threads.
__global__ __launch_bounds__(64) void k_lsm_final(const float* __restrict__ pmax,
                                                  const float* __restrict__ psum,
                                                  float* __restrict__ lse) {
    int b = threadIdx.x;
    float m = -1e30f;
    #pragma unroll
    for (int c = 0; c < 8; ++c) m = fmaxf(m, pmax[c * 64 + b]);
    float s = 0.f;
    #pragma unroll
    for (int c = 0; c < 8; ++c) s += psum[c * 64 + b] * __expf(pmax[c * 64 + b] - m);
    lse[b] = m + __logf(s);
}

// K8c: out = logits - lse[b].  2000 blocks x 256 thr x 4 elems.
__global__ __launch_bounds__(256) void k_lsm_write(const float* __restrict__ logits,
                                                   const float* __restrict__ lse,
                                                   float* __restrict__ out) {
    size_t i4 = ((size_t)blockIdx.x * 256 + threadIdx.x) * 4;
    int b = (int)(i4 / V);
    float l = lse[b];
    float4 x = *reinterpret_cast<const float4*>(&logits[i4]);
    x.x -= l; x.y -= l; x.z -= l; x.w -= l;
    *reinterpret_cast<float4*>(&out[i4]) = x;
}

// ---------------------------------------------------------------------------
extern "C" void kernel_launch(void* const* d_in, const int* in_sizes, int n_in,
                              void* d_out, int out_size, void* d_ws, size_t ws_size,
                              hipStream_t stream) {
    const int*   inp    = (const int*)  d_in[0];
    const float* loc    = (const float*)d_in[1];
    const float* hprev  = (const float*)d_in[2];
    const float* cprev  = (const float*)d_in[3];
    const float* enc    = (const float*)d_in[4];
    const float* emb    = (const float*)d_in[5];
    const float* W_ih   = (const float*)d_in[6];
    const float* W_hh   = (const float*)d_in[7];
    const float* b_ih   = (const float*)d_in[8];
    const float* b_hh   = (const float*)d_in[9];
    const float* W_attn = (const float*)d_in[10];
    const float* b_attn = (const float*)d_in[11];
    const float* beta   = (const float*)d_in[12];
    const float* W_oc   = (const float*)d_in[13];
    const float* b_oc   = (const float*)d_in[14];
    const float* W_out  = (const float*)d_in[15];
    const float* b_out  = (const float*)d_in[16];

    float* out = (float*)d_out;
    float* out_co = out + (size_t)B * V;
    float* out_h  = out_co + B * H;
    float* out_c  = out_h  + B * H;

    float* ws = (float*)d_ws;
    float* xprevT = ws;                                  //    81920
    float* hnewT  = xprevT + 1280 * 64;                  //    32768
    float* hW     = hnewT  + H * 64;                     //    32768
    float* pe     = hW     + H * 64;                     //  4*65536
    float* attnw  = pe     + 4 * M_TOT;                  //    65536
    float* ctxp   = attnw  + M_TOT;                      //  1048576
    float* ctxT   = ctxp   + 32 * 64 * H;                //    32768
    float* logits = ctxT   + H * 64;                     //  2048000
    float* pmax   = logits + (size_t)B * V;              //      512
    float* psum   = pmax   + 512;                        //      512
    float* lse    = psum   + 512;                        //       64
    unsigned short* Wf = (unsigned short*)(lse + 64);    //   262144 u16

    k_conv_w<<<128, 256, 0, stream>>>(W_attn, Wf);
    k_build <<<320, 256, 0, stream>>>(inp, loc, hprev, emb, xprevT);
    k_lstm  <<<512, 256, 0, stream>>>(W_ih, W_hh, b_ih, b_hh, xprevT, cprev,
                                      out_h, out_c, hnewT);
    k_hw    <<<128, 256, 0, stream>>>(W_attn, b_attn, hnewT, hW);
    k_energy_v4<<<2048, 256, 0, stream>>>(enc, Wf, hW, beta, pe);
    k_softmax_l<<<64, 256, 0, stream>>>(pe, attnw);
    k_ctx_part <<<dim3(32, 64), 128, 0, stream>>>(attnw, enc, ctxp);
    k_ctx_reduce<<<128, 256, 0, stream>>>(ctxp, ctxT);
    k_co    <<<128, 256, 0, stream>>>(W_oc, b_oc, hnewT, ctxT, out_co);
    k_logits_v2<<<500, 256, 0, stream>>>(out_co, W_out, b_out, logits);
    k_lsm_part<<<dim3(8, 64), 256, 0, stream>>>(logits, pmax, psum);
    k_lsm_final<<<1, 64, 0, stream>>>(pmax, psum, lse);
    k_lsm_write<<<2000, 256, 0, stream>>>(logits, lse, out);
}